// Round 9
// baseline (350.776 us; speedup 1.0000x reference)
//
#include <hip/hip_runtime.h>
#include <hip/hip_fp16.h>
#include <math.h>

#define N_NODES 50000
#define N_EDGES 600000
#define N_GRAPHS 64
#define DFEAT 128
#define H3 384
#define OUTD 10
#define SCAN_BLOCKS 196   // 196*256 = 50176 >= 50000
#define APAD 136          // fp16 LDS row pad: 272B stride -> conflict-free b128 reads

typedef _Float16 f16x8 __attribute__((ext_vector_type(8)));
typedef float f32x4 __attribute__((ext_vector_type(4)));

// ---------------- degree histogram (in-degree at dst) + per-edge rank ----------------
__global__ __launch_bounds__(256) void k_deg(const int* __restrict__ ei, int* __restrict__ deg,
                                             int* __restrict__ rank) {
    int e = blockIdx.x * 256 + threadIdx.x;
    if (e >= N_EDGES) return;
    int dst = ei[N_EDGES + e];
    rank[e] = atomicAdd(&deg[dst], 1);
}

// ---------------- hierarchical scan, stage 1: per-block partial sums ----------------
__global__ __launch_bounds__(256) void k_part(const int* __restrict__ deg, int* __restrict__ part) {
    __shared__ int red[256];
    int tid = threadIdx.x;
    int i = blockIdx.x * 256 + tid;
    red[tid] = (i < N_NODES) ? deg[i] : 0;
    __syncthreads();
    for (int s = 128; s > 0; s >>= 1) {
        if (tid < s) red[tid] += red[tid + s];
        __syncthreads();
    }
    if (tid == 0) part[blockIdx.x] = red[0];
}

// ---------------- stage 2: one-block scan of the 196 partials -> exclusive bases ----------------
__global__ __launch_bounds__(256) void k_scanpart(const int* __restrict__ part, int* __restrict__ base) {
    __shared__ int buf[256];
    int tid = threadIdx.x;
    int v = (tid < SCAN_BLOCKS) ? part[tid] : 0;
    buf[tid] = v;
    __syncthreads();
    for (int d = 1; d < 256; d <<= 1) {
        int t = (tid >= d) ? buf[tid - d] : 0;
        __syncthreads();
        buf[tid] += t;
        __syncthreads();
    }
    if (tid < SCAN_BLOCKS) base[tid] = buf[tid] - v;  // exclusive
}

// ---------------- stage 3: block-local scan + base -> offs; fused dinv ----------------
__global__ __launch_bounds__(256) void k_offsets(const int* __restrict__ deg, const int* __restrict__ base,
                                                 int* __restrict__ offs, float* __restrict__ dinv) {
    __shared__ int buf[256];
    int tid = threadIdx.x;
    int i = blockIdx.x * 256 + tid;
    int v = (i < N_NODES) ? deg[i] : 0;
    buf[tid] = v;
    __syncthreads();
    for (int d = 1; d < 256; d <<= 1) {
        int t = (tid >= d) ? buf[tid - d] : 0;
        __syncthreads();
        buf[tid] += t;
        __syncthreads();
    }
    if (i < N_NODES) {
        int excl = base[blockIdx.x] + buf[tid] - v;
        offs[i] = excl;
        dinv[i] = rsqrtf((float)v + 1.0f);
        if (i == N_NODES - 1) offs[N_NODES] = base[blockIdx.x] + buf[tid];  // total == N_EDGES
    }
}

// ---------------- fill CSR buckets: pure scatter, no atomics (rank precomputed) ----------------
__global__ __launch_bounds__(256) void k_fill(const int* __restrict__ ei, const int* __restrict__ offs,
                                              const int* __restrict__ rank, int* __restrict__ srcs) {
    int e = blockIdx.x * 256 + threadIdx.x;
    if (e >= N_EDGES) return;
    int s = ei[e];
    int t = ei[N_EDGES + e];
    srcs[offs[t] + rank[e]] = s;
}

// ---------------- prep: all 3 W's fp32[k][n] -> fp16 transposed [n][k]; zero pooled ----------------
__global__ __launch_bounds__(256) void k_prep(const float* __restrict__ W1, const float* __restrict__ W2,
                                              const float* __restrict__ W3, _Float16* __restrict__ Wt,
                                              float* __restrict__ pooled) {
    int b = blockIdx.x;
    if (b < 192) {
        int idx = b * 256 + threadIdx.x;       // 0..49151
        int l = idx >> 14, r = idx & 16383;
        const float* W = (l == 0) ? W1 : (l == 1) ? W2 : W3;
        int k = r >> 7, n = r & 127;
        Wt[l * 16384 + n * 128 + k] = (_Float16)W[k * 128 + n];
    } else {
        int idx = (b - 192) * 256 + threadIdx.x;
        if (idx < N_GRAPHS * H3) pooled[idx] = 0.0f;
    }
}

// ---------------- T[Mx128](fp16) = A[Mx128] @ W (via fp16 MFMA) ----------------
// A is fp32 (layer 1: x) or fp16 (layers 2/3: H). 64 rows/block, 4 waves x 16 rows.
// Operand-swap mfma(b,a,acc): D col(lane&15)=node row, 4 acc regs = 4 consecutive cols.
template <bool A_FP16>
__global__ __launch_bounds__(256) void gemm_mfma(const void* __restrict__ Aptr, const _Float16* __restrict__ Wt,
                                                 __half* __restrict__ T, int M) {
    __shared__ _Float16 As[64 * APAD];    // 17.4 KB
    __shared__ _Float16 Ws[128 * APAD];   // 34.8 KB
    int tid = threadIdx.x;
    int base = blockIdx.x * 64;
    // stage Wt: 128 rows x 16 chunks of 8 f16
    for (int c = tid; c < 2048; c += 256) {
        int n = c >> 4, c8 = (c & 15) << 3;
        *(f16x8*)&Ws[n * APAD + c8] = *(const f16x8*)&Wt[n * 128 + c8];
    }
    // stage A: 64 rows x 16 chunks of 8
    for (int c = tid; c < 1024; c += 256) {
        int r = c >> 4, c8 = (c & 15) << 3;
        int gr = base + r; if (gr >= M) gr = M - 1;
        if (A_FP16) {
            const _Float16* A = (const _Float16*)Aptr;
            *(f16x8*)&As[r * APAD + c8] = *(const f16x8*)&A[(size_t)gr * 128 + c8];
        } else {
            const float* A = (const float*)Aptr;
            const float* src = A + (size_t)gr * 128 + c8;
            float4 v0 = *(const float4*)(src);
            float4 v1 = *(const float4*)(src + 4);
            f16x8 h;
            h[0] = (_Float16)v0.x; h[1] = (_Float16)v0.y; h[2] = (_Float16)v0.z; h[3] = (_Float16)v0.w;
            h[4] = (_Float16)v1.x; h[5] = (_Float16)v1.y; h[6] = (_Float16)v1.z; h[7] = (_Float16)v1.w;
            *(f16x8*)&As[r * APAD + c8] = h;
        }
    }
    __syncthreads();
    int wave = tid >> 6, lane = tid & 63;
    int m = lane & 15, quad = lane >> 4;
    f32x4 acc[8];
#pragma unroll
    for (int ct = 0; ct < 8; ++ct) acc[ct] = (f32x4){0.f, 0.f, 0.f, 0.f};
#pragma unroll
    for (int kc = 0; kc < 4; ++kc) {
        f16x8 a = *(const f16x8*)&As[(wave * 16 + m) * APAD + kc * 32 + quad * 8];
#pragma unroll
        for (int ct = 0; ct < 8; ++ct) {
            f16x8 b = *(const f16x8*)&Ws[(ct * 16 + m) * APAD + kc * 32 + quad * 8];
            acc[ct] = __builtin_amdgcn_mfma_f32_16x16x32_f16(b, a, acc[ct], 0, 0, 0);
        }
    }
    int node = base + wave * 16 + m;
    if (node < M) {
#pragma unroll
        for (int ct = 0; ct < 8; ++ct) {
            int col = ct * 16 + quad * 4;
            __half2 h0 = __floats2half2_rn(acc[ct][0], acc[ct][1]);
            __half2 h1 = __floats2half2_rn(acc[ct][2], acc[ct][3]);
            *(__half2*)(T + (size_t)node * 128 + col)     = h0;
            *(__half2*)(T + (size_t)node * 128 + col + 2) = h1;
        }
    }
}

// ---------------- fused gather + pool: H = Ahat*T + b, pooled += per-graph sums ----------------
// 512 threads = 8 waves, 1 node/wave, 64 lanes x 2 dims. 6250 blocks exactly (50000/8).
// coef recomputed: H[n] = di * sum_e(dinv[s_e]*T[s_e]) + di^2*T[n] + b. 8x unroll.
// Pool: fp32 accs reduced in LDS (single-graph fast path), 128 atomics/block.
__global__ __launch_bounds__(512) void gather_pool(const __half2* __restrict__ T2, const int* __restrict__ srcs,
                                                   const int* __restrict__ offs,
                                                   const float* __restrict__ dinv, const float* __restrict__ bias,
                                                   const int* __restrict__ batch,
                                                   __half2* __restrict__ H2, float* __restrict__ pooled,
                                                   int colOff, int storeH) {
    __shared__ float2 psum[8][64];
    __shared__ int pg[8];
    int wave = threadIdx.x >> 6, lane = threadIdx.x & 63;
    int node = blockIdx.x * 8 + wave;
    float di = dinv[node];
    float2 b2 = *(const float2*)(bias + lane * 2);
    float2 sf = __half22float2(T2[(size_t)node * 64 + lane]);
    float sx = 0.0f, sy = 0.0f;  // edge-sum, weighted by dinv[s] only
    int lo = offs[node], hi = offs[node + 1];
    int e = lo;
    for (; e + 8 <= hi; e += 8) {
        int s0 = srcs[e + 0], s1 = srcs[e + 1], s2 = srcs[e + 2], s3 = srcs[e + 3];
        int s4 = srcs[e + 4], s5 = srcs[e + 5], s6 = srcs[e + 6], s7 = srcs[e + 7];
        float c0 = dinv[s0], c1 = dinv[s1], c2 = dinv[s2], c3 = dinv[s3];
        float c4 = dinv[s4], c5 = dinv[s5], c6 = dinv[s6], c7 = dinv[s7];
        float2 t0 = __half22float2(T2[(size_t)s0 * 64 + lane]);
        float2 t1 = __half22float2(T2[(size_t)s1 * 64 + lane]);
        float2 t2 = __half22float2(T2[(size_t)s2 * 64 + lane]);
        float2 t3 = __half22float2(T2[(size_t)s3 * 64 + lane]);
        float2 t4 = __half22float2(T2[(size_t)s4 * 64 + lane]);
        float2 t5 = __half22float2(T2[(size_t)s5 * 64 + lane]);
        float2 t6 = __half22float2(T2[(size_t)s6 * 64 + lane]);
        float2 t7 = __half22float2(T2[(size_t)s7 * 64 + lane]);
        sx += t0.x * c0; sy += t0.y * c0;
        sx += t1.x * c1; sy += t1.y * c1;
        sx += t2.x * c2; sy += t2.y * c2;
        sx += t3.x * c3; sy += t3.y * c3;
        sx += t4.x * c4; sy += t4.y * c4;
        sx += t5.x * c5; sy += t5.y * c5;
        sx += t6.x * c6; sy += t6.y * c6;
        sx += t7.x * c7; sy += t7.y * c7;
    }
    for (; e + 4 <= hi; e += 4) {
        int s0 = srcs[e + 0], s1 = srcs[e + 1], s2 = srcs[e + 2], s3 = srcs[e + 3];
        float c0 = dinv[s0], c1 = dinv[s1], c2 = dinv[s2], c3 = dinv[s3];
        float2 t0 = __half22float2(T2[(size_t)s0 * 64 + lane]);
        float2 t1 = __half22float2(T2[(size_t)s1 * 64 + lane]);
        float2 t2 = __half22float2(T2[(size_t)s2 * 64 + lane]);
        float2 t3 = __half22float2(T2[(size_t)s3 * 64 + lane]);
        sx += t0.x * c0; sy += t0.y * c0;
        sx += t1.x * c1; sy += t1.y * c1;
        sx += t2.x * c2; sy += t2.y * c2;
        sx += t3.x * c3; sy += t3.y * c3;
    }
    for (; e < hi; ++e) {
        int s = srcs[e];
        float c = dinv[s];
        float2 t = __half22float2(T2[(size_t)s * 64 + lane]);
        sx += t.x * c; sy += t.y * c;
    }
    float accx = di * sx + sf.x * (di * di) + b2.x;
    float accy = di * sy + sf.y * (di * di) + b2.y;
    if (storeH) H2[(size_t)node * 64 + lane] = __floats2half2_rn(accx, accy);
    // ---- fused pooling ----
    psum[wave][lane] = make_float2(accx, accy);
    if (lane == 0) pg[wave] = batch[node];
    __syncthreads();
    if (wave == 0) {
        int g0 = pg[0];
        bool uni = (pg[1] == g0) & (pg[2] == g0) & (pg[3] == g0) &
                   (pg[4] == g0) & (pg[5] == g0) & (pg[6] == g0) & (pg[7] == g0);
        if (uni) {
            float vx = 0.0f, vy = 0.0f;
#pragma unroll
            for (int w = 0; w < 8; ++w) { float2 v = psum[w][lane]; vx += v.x; vy += v.y; }
            atomicAdd(&pooled[g0 * H3 + colOff + lane * 2],     vx);
            atomicAdd(&pooled[g0 * H3 + colOff + lane * 2 + 1], vy);
        } else {
#pragma unroll
            for (int w = 0; w < 8; ++w) {
                float2 v = psum[w][lane];
                atomicAdd(&pooled[pg[w] * H3 + colOff + lane * 2],     v.x);
                atomicAdd(&pooled[pg[w] * H3 + colOff + lane * 2 + 1], v.y);
            }
        }
    }
}

// ---------------- MLP head + log_softmax, one block per graph; cnt via binary search ----------------
__global__ __launch_bounds__(384) void mlp_kernel(const float* __restrict__ pooled,
                                                  const int* __restrict__ batch,
                                                  const float* __restrict__ l1W, const float* __restrict__ l1b,
                                                  const float* __restrict__ l2W, const float* __restrict__ l2b,
                                                  float* __restrict__ out) {
    __shared__ float p[H3];
    __shared__ float hid[H3];
    __shared__ float o10[OUTD];
    __shared__ int bnd[2];
    int g = blockIdx.x, tid = threadIdx.x;
    if (tid < 2) {
        int target = g + tid;  // lower_bound(batch, target)
        int lo = 0, hi = N_NODES;
        while (lo < hi) {
            int mid = (lo + hi) >> 1;
            if (batch[mid] < target) lo = mid + 1; else hi = mid;
        }
        bnd[tid] = lo;
    }
    __syncthreads();
    float inv = 1.0f / fmaxf((float)(bnd[1] - bnd[0]), 1.0f);
    p[tid] = pooled[g * H3 + tid] * inv;
    __syncthreads();
    float acc = l1b[tid];
    for (int k = 0; k < H3; ++k) acc += p[k] * l1W[k * H3 + tid];
    hid[tid] = fmaxf(acc, 0.0f);
    __syncthreads();
    if (tid < OUTD) {
        float o = l2b[tid];
        for (int k = 0; k < H3; ++k) o += hid[k] * l2W[k * OUTD + tid];
        o10[tid] = o;
        out[g * OUTD + tid] = o;
    }
    __syncthreads();
    if (tid == 0) {
        float m = o10[0];
        for (int j = 1; j < OUTD; ++j) m = fmaxf(m, o10[j]);
        float s = 0.0f;
        for (int j = 0; j < OUTD; ++j) s += expf(o10[j] - m);
        float lse = m + logf(s);
        for (int j = 0; j < OUTD; ++j) out[N_GRAPHS * OUTD + g * OUTD + j] = o10[j] - lse;
    }
}

extern "C" void kernel_launch(void* const* d_in, const int* in_sizes, int n_in,
                              void* d_out, int out_size, void* d_ws, size_t ws_size,
                              hipStream_t stream) {
    const float* x      = (const float*)d_in[0];
    const float* W1     = (const float*)d_in[1];
    const float* b1     = (const float*)d_in[2];
    const float* W2     = (const float*)d_in[3];
    const float* b2     = (const float*)d_in[4];
    const float* W3     = (const float*)d_in[5];
    const float* b3     = (const float*)d_in[6];
    const float* lin1_W = (const float*)d_in[7];
    const float* lin1_b = (const float*)d_in[8];
    const float* lin2_W = (const float*)d_in[9];
    const float* lin2_b = (const float*)d_in[10];
    const int* edge_index = (const int*)d_in[11];
    const int* batch      = (const int*)d_in[12];

    char* ws = (char*)d_ws;
    auto alloc = [&](size_t bytes) -> void* {
        void* p = (void*)ws;
        ws += (bytes + 255) & ~(size_t)255;
        return p;
    };
    int*   deg    = (int*)  alloc((size_t)N_NODES * 4);
    int*   part   = (int*)  alloc((size_t)SCAN_BLOCKS * 4);
    int*   pbase  = (int*)  alloc((size_t)SCAN_BLOCKS * 4);
    int*   offs   = (int*)  alloc((size_t)(N_NODES + 1) * 4);
    int*   rank   = (int*)  alloc((size_t)N_EDGES * 4);
    float* dinv   = (float*)alloc((size_t)N_NODES * 4);
    int*   srcs   = (int*)  alloc((size_t)N_EDGES * 4);
    __half* T     = (__half*)alloc((size_t)N_NODES * 128 * 2);
    __half* H     = (__half*)alloc((size_t)N_NODES * 128 * 2);
    _Float16* Wt  = (_Float16*)alloc((size_t)3 * 128 * 128 * 2);
    float* pooled = (float*)alloc((size_t)N_GRAPHS * H3 * 4);

    hipMemsetAsync(deg, 0, (size_t)N_NODES * 4, stream);
    k_deg<<<(N_EDGES + 255) / 256, 256, 0, stream>>>(edge_index, deg, rank);
    k_part<<<SCAN_BLOCKS, 256, 0, stream>>>(deg, part);
    k_scanpart<<<1, 256, 0, stream>>>(part, pbase);
    k_offsets<<<SCAN_BLOCKS, 256, 0, stream>>>(deg, pbase, offs, dinv);
    k_fill<<<(N_EDGES + 255) / 256, 256, 0, stream>>>(edge_index, offs, rank, srcs);
    k_prep<<<288, 256, 0, stream>>>(W1, W2, W3, Wt, pooled);

    const float* bs[3] = {b1, b2, b3};
    for (int l = 0; l < 3; ++l) {
        if (l == 0)
            gemm_mfma<false><<<(N_NODES + 63) / 64, 256, 0, stream>>>(x, Wt, T, N_NODES);
        else
            gemm_mfma<true><<<(N_NODES + 63) / 64, 256, 0, stream>>>(H, Wt + (size_t)l * 16384, T, N_NODES);
        gather_pool<<<N_NODES / 8, 512, 0, stream>>>((const __half2*)T, srcs, offs, dinv, bs[l], batch,
                                                     (__half2*)H, pooled, l * 128, (l < 2) ? 1 : 0);
    }
    mlp_kernel<<<N_GRAPHS, 384, 0, stream>>>(pooled, batch, lin1_W, lin1_b, lin2_W, lin2_b, (float*)d_out);
}

// Round 10
// 318.770 us; speedup vs baseline: 1.1004x; 1.1004x over previous
//
#include <hip/hip_runtime.h>
#include <hip/hip_fp16.h>
#include <math.h>

#define N_NODES 50000
#define N_EDGES 600000
#define N_GRAPHS 64
#define DFEAT 128
#define H3 384
#define OUTD 10
#define SCAN_BLOCKS 196   // 196*256 = 50176 >= 50000
#define POOL_CHUNKS 16    // blocks per graph in pooling
#define APAD 136          // fp16 LDS row pad: 272B stride -> conflict-free b128 reads

typedef _Float16 f16x8 __attribute__((ext_vector_type(8)));
typedef float f32x4 __attribute__((ext_vector_type(4)));

// ---------------- degree histogram (in-degree at dst) + per-edge rank ----------------
__global__ __launch_bounds__(256) void k_deg(const int* __restrict__ ei, int* __restrict__ deg,
                                             int* __restrict__ rank) {
    int e = blockIdx.x * 256 + threadIdx.x;
    if (e >= N_EDGES) return;
    int dst = ei[N_EDGES + e];
    rank[e] = atomicAdd(&deg[dst], 1);
}

// ---------------- hierarchical scan, stage 1: per-block partial sums ----------------
__global__ __launch_bounds__(256) void k_part(const int* __restrict__ deg, int* __restrict__ part) {
    __shared__ int red[256];
    int tid = threadIdx.x;
    int i = blockIdx.x * 256 + tid;
    red[tid] = (i < N_NODES) ? deg[i] : 0;
    __syncthreads();
    for (int s = 128; s > 0; s >>= 1) {
        if (tid < s) red[tid] += red[tid + s];
        __syncthreads();
    }
    if (tid == 0) part[blockIdx.x] = red[0];
}

// ---------------- stage 2: one-block scan of the 196 partials -> exclusive bases ----------------
__global__ __launch_bounds__(256) void k_scanpart(const int* __restrict__ part, int* __restrict__ base) {
    __shared__ int buf[256];
    int tid = threadIdx.x;
    int v = (tid < SCAN_BLOCKS) ? part[tid] : 0;
    buf[tid] = v;
    __syncthreads();
    for (int d = 1; d < 256; d <<= 1) {
        int t = (tid >= d) ? buf[tid - d] : 0;
        __syncthreads();
        buf[tid] += t;
        __syncthreads();
    }
    if (tid < SCAN_BLOCKS) base[tid] = buf[tid] - v;  // exclusive
}

// ---------------- stage 3: block-local scan + base -> offs; fused dinv ----------------
__global__ __launch_bounds__(256) void k_offsets(const int* __restrict__ deg, const int* __restrict__ base,
                                                 int* __restrict__ offs, float* __restrict__ dinv) {
    __shared__ int buf[256];
    int tid = threadIdx.x;
    int i = blockIdx.x * 256 + tid;
    int v = (i < N_NODES) ? deg[i] : 0;
    buf[tid] = v;
    __syncthreads();
    for (int d = 1; d < 256; d <<= 1) {
        int t = (tid >= d) ? buf[tid - d] : 0;
        __syncthreads();
        buf[tid] += t;
        __syncthreads();
    }
    if (i < N_NODES) {
        int excl = base[blockIdx.x] + buf[tid] - v;
        offs[i] = excl;
        dinv[i] = rsqrtf((float)v + 1.0f);
        if (i == N_NODES - 1) offs[N_NODES] = base[blockIdx.x] + buf[tid];  // total == N_EDGES
    }
}

// ---------------- fill CSR buckets: pure scatter, no atomics (rank precomputed) ----------------
__global__ __launch_bounds__(256) void k_fill(const int* __restrict__ ei, const int* __restrict__ offs,
                                              const int* __restrict__ rank, int* __restrict__ srcs) {
    int e = blockIdx.x * 256 + threadIdx.x;
    if (e >= N_EDGES) return;
    int s = ei[e];
    int t = ei[N_EDGES + e];
    srcs[offs[t] + rank[e]] = s;
}

// ---------------- prep: all 3 W's fp32[k][n] -> fp16 transposed [n][k]; zero pooled ----------------
__global__ __launch_bounds__(256) void k_prep(const float* __restrict__ W1, const float* __restrict__ W2,
                                              const float* __restrict__ W3, _Float16* __restrict__ Wt,
                                              float* __restrict__ pooled) {
    int b = blockIdx.x;
    if (b < 192) {
        int idx = b * 256 + threadIdx.x;       // 0..49151
        int l = idx >> 14, r = idx & 16383;
        const float* W = (l == 0) ? W1 : (l == 1) ? W2 : W3;
        int k = r >> 7, n = r & 127;
        Wt[l * 16384 + n * 128 + k] = (_Float16)W[k * 128 + n];
    } else {
        int idx = (b - 192) * 256 + threadIdx.x;
        if (idx < N_GRAPHS * H3) pooled[idx] = 0.0f;
    }
}

// ---------------- T[Mx128](fp16) = A[Mx128] @ W (via fp16 MFMA) ----------------
// A is fp32 (layer 1: x) or fp16 (layers 2/3: H). 64 rows/block, 4 waves x 16 rows.
// Operand-swap mfma(b,a,acc): D col(lane&15)=node row, 4 acc regs = 4 consecutive cols.
template <bool A_FP16>
__global__ __launch_bounds__(256) void gemm_mfma(const void* __restrict__ Aptr, const _Float16* __restrict__ Wt,
                                                 __half* __restrict__ T, int M) {
    __shared__ _Float16 As[64 * APAD];    // 17.4 KB
    __shared__ _Float16 Ws[128 * APAD];   // 34.8 KB
    int tid = threadIdx.x;
    int base = blockIdx.x * 64;
    // stage Wt: 128 rows x 16 chunks of 8 f16
    for (int c = tid; c < 2048; c += 256) {
        int n = c >> 4, c8 = (c & 15) << 3;
        *(f16x8*)&Ws[n * APAD + c8] = *(const f16x8*)&Wt[n * 128 + c8];
    }
    // stage A: 64 rows x 16 chunks of 8
    for (int c = tid; c < 1024; c += 256) {
        int r = c >> 4, c8 = (c & 15) << 3;
        int gr = base + r; if (gr >= M) gr = M - 1;
        if (A_FP16) {
            const _Float16* A = (const _Float16*)Aptr;
            *(f16x8*)&As[r * APAD + c8] = *(const f16x8*)&A[(size_t)gr * 128 + c8];
        } else {
            const float* A = (const float*)Aptr;
            const float* src = A + (size_t)gr * 128 + c8;
            float4 v0 = *(const float4*)(src);
            float4 v1 = *(const float4*)(src + 4);
            f16x8 h;
            h[0] = (_Float16)v0.x; h[1] = (_Float16)v0.y; h[2] = (_Float16)v0.z; h[3] = (_Float16)v0.w;
            h[4] = (_Float16)v1.x; h[5] = (_Float16)v1.y; h[6] = (_Float16)v1.z; h[7] = (_Float16)v1.w;
            *(f16x8*)&As[r * APAD + c8] = h;
        }
    }
    __syncthreads();
    int wave = tid >> 6, lane = tid & 63;
    int m = lane & 15, quad = lane >> 4;
    f32x4 acc[8];
#pragma unroll
    for (int ct = 0; ct < 8; ++ct) acc[ct] = (f32x4){0.f, 0.f, 0.f, 0.f};
#pragma unroll
    for (int kc = 0; kc < 4; ++kc) {
        f16x8 a = *(const f16x8*)&As[(wave * 16 + m) * APAD + kc * 32 + quad * 8];
#pragma unroll
        for (int ct = 0; ct < 8; ++ct) {
            f16x8 b = *(const f16x8*)&Ws[(ct * 16 + m) * APAD + kc * 32 + quad * 8];
            acc[ct] = __builtin_amdgcn_mfma_f32_16x16x32_f16(b, a, acc[ct], 0, 0, 0);
        }
    }
    int node = base + wave * 16 + m;
    if (node < M) {
#pragma unroll
        for (int ct = 0; ct < 8; ++ct) {
            int col = ct * 16 + quad * 4;
            __half2 h0 = __floats2half2_rn(acc[ct][0], acc[ct][1]);
            __half2 h1 = __floats2half2_rn(acc[ct][2], acc[ct][3]);
            *(__half2*)(T + (size_t)node * 128 + col)     = h0;
            *(__half2*)(T + (size_t)node * 128 + col + 2) = h1;
        }
    }
}

// ---------------- per-node gather-accumulate: H(fp16) = Ahat * T(fp16) + b ----------------
// 1 wave per node, waves fully independent (no cross-wave sync -> no straggler coupling).
// 2 nodes per 128-thread block. coef recomputed: H[n] = di*sum_e(dinv[s_e]*T[s_e]) + di^2*T[n] + b.
__global__ __launch_bounds__(128) void gather_agg(const __half2* __restrict__ T2, const int* __restrict__ srcs,
                                                  const int* __restrict__ offs,
                                                  const float* __restrict__ dinv, const float* __restrict__ bias,
                                                  __half2* __restrict__ H2) {
    int node = blockIdx.x * 2 + (threadIdx.x >> 6);
    int lane = threadIdx.x & 63;   // dims 2*lane, 2*lane+1
    if (node >= N_NODES) return;
    float di = dinv[node];
    float2 b2 = *(const float2*)(bias + lane * 2);
    float2 sf = __half22float2(T2[(size_t)node * 64 + lane]);
    float sx = 0.0f, sy = 0.0f;  // edge-sum, weighted by dinv[s] only
    int lo = offs[node], hi = offs[node + 1];
    int e = lo;
    for (; e + 8 <= hi; e += 8) {
        int s0 = srcs[e + 0], s1 = srcs[e + 1], s2 = srcs[e + 2], s3 = srcs[e + 3];
        int s4 = srcs[e + 4], s5 = srcs[e + 5], s6 = srcs[e + 6], s7 = srcs[e + 7];
        float c0 = dinv[s0], c1 = dinv[s1], c2 = dinv[s2], c3 = dinv[s3];
        float c4 = dinv[s4], c5 = dinv[s5], c6 = dinv[s6], c7 = dinv[s7];
        float2 t0 = __half22float2(T2[(size_t)s0 * 64 + lane]);
        float2 t1 = __half22float2(T2[(size_t)s1 * 64 + lane]);
        float2 t2 = __half22float2(T2[(size_t)s2 * 64 + lane]);
        float2 t3 = __half22float2(T2[(size_t)s3 * 64 + lane]);
        float2 t4 = __half22float2(T2[(size_t)s4 * 64 + lane]);
        float2 t5 = __half22float2(T2[(size_t)s5 * 64 + lane]);
        float2 t6 = __half22float2(T2[(size_t)s6 * 64 + lane]);
        float2 t7 = __half22float2(T2[(size_t)s7 * 64 + lane]);
        sx += t0.x * c0; sy += t0.y * c0;
        sx += t1.x * c1; sy += t1.y * c1;
        sx += t2.x * c2; sy += t2.y * c2;
        sx += t3.x * c3; sy += t3.y * c3;
        sx += t4.x * c4; sy += t4.y * c4;
        sx += t5.x * c5; sy += t5.y * c5;
        sx += t6.x * c6; sy += t6.y * c6;
        sx += t7.x * c7; sy += t7.y * c7;
    }
    for (; e + 4 <= hi; e += 4) {
        int s0 = srcs[e + 0], s1 = srcs[e + 1], s2 = srcs[e + 2], s3 = srcs[e + 3];
        float c0 = dinv[s0], c1 = dinv[s1], c2 = dinv[s2], c3 = dinv[s3];
        float2 t0 = __half22float2(T2[(size_t)s0 * 64 + lane]);
        float2 t1 = __half22float2(T2[(size_t)s1 * 64 + lane]);
        float2 t2 = __half22float2(T2[(size_t)s2 * 64 + lane]);
        float2 t3 = __half22float2(T2[(size_t)s3 * 64 + lane]);
        sx += t0.x * c0; sy += t0.y * c0;
        sx += t1.x * c1; sy += t1.y * c1;
        sx += t2.x * c2; sy += t2.y * c2;
        sx += t3.x * c3; sy += t3.y * c3;
    }
    for (; e < hi; ++e) {
        int s = srcs[e];
        float c = dinv[s];
        float2 t = __half22float2(T2[(size_t)s * 64 + lane]);
        sx += t.x * c; sy += t.y * c;
    }
    float accx = di * sx + sf.x * (di * di) + b2.x;
    float accy = di * sy + sf.y * (di * di) + b2.y;
    H2[(size_t)node * 64 + lane] = __floats2half2_rn(accx, accy);
}

// ---------------- segment-sum pooling, chunked, fp16 H (batch sorted) ----------------
// 256 threads = 4 rows x 64 lane-pairs (__half2 = 2 dims per lane).
__global__ __launch_bounds__(256) void pool_kernel(const __half2* __restrict__ H2, const int* __restrict__ batch,
                                                   float* __restrict__ pooled, int colOff) {
    __shared__ int bounds[2];
    __shared__ float2 red[256];
    int g = blockIdx.x >> 4;        // / POOL_CHUNKS
    int chunk = blockIdx.x & (POOL_CHUNKS - 1);
    int tid = threadIdx.x;
    int d2 = tid & 63, sub = tid >> 6;  // 4 row-accumulators
    if (tid < 2) {
        int target = g + tid;  // lower_bound(batch, target)
        int lo = 0, hi = N_NODES;
        while (lo < hi) {
            int mid = (lo + hi) >> 1;
            if (batch[mid] < target) lo = mid + 1; else hi = mid;
        }
        bounds[tid] = lo;
    }
    __syncthreads();
    int lo = bounds[0], hi = bounds[1];
    int n = hi - lo;
    int per = (n + POOL_CHUNKS - 1) / POOL_CHUNKS;
    int s = lo + chunk * per;
    int e = s + per; if (e > hi) e = hi;
    float ax = 0.0f, ay = 0.0f;
    for (int r = s + sub; r < e; r += 4) {
        float2 v = __half22float2(H2[(size_t)r * 64 + d2]);
        ax += v.x; ay += v.y;
    }
    red[tid] = make_float2(ax, ay);
    __syncthreads();
    if (sub == 0 && s < e) {
        float2 v0 = red[d2], v1 = red[64 + d2], v2 = red[128 + d2], v3 = red[192 + d2];
        float vx = v0.x + v1.x + v2.x + v3.x;
        float vy = v0.y + v1.y + v2.y + v3.y;
        atomicAdd(&pooled[g * H3 + colOff + d2 * 2],     vx);
        atomicAdd(&pooled[g * H3 + colOff + d2 * 2 + 1], vy);
    }
}

// ---------------- MLP head + log_softmax, one block per graph; cnt via binary search ----------------
__global__ __launch_bounds__(384) void mlp_kernel(const float* __restrict__ pooled,
                                                  const int* __restrict__ batch,
                                                  const float* __restrict__ l1W, const float* __restrict__ l1b,
                                                  const float* __restrict__ l2W, const float* __restrict__ l2b,
                                                  float* __restrict__ out) {
    __shared__ float p[H3];
    __shared__ float hid[H3];
    __shared__ float o10[OUTD];
    __shared__ int bnd[2];
    int g = blockIdx.x, tid = threadIdx.x;
    if (tid < 2) {
        int target = g + tid;  // lower_bound(batch, target)
        int lo = 0, hi = N_NODES;
        while (lo < hi) {
            int mid = (lo + hi) >> 1;
            if (batch[mid] < target) lo = mid + 1; else hi = mid;
        }
        bnd[tid] = lo;
    }
    __syncthreads();
    float inv = 1.0f / fmaxf((float)(bnd[1] - bnd[0]), 1.0f);
    p[tid] = pooled[g * H3 + tid] * inv;
    __syncthreads();
    float acc = l1b[tid];
    for (int k = 0; k < H3; ++k) acc += p[k] * l1W[k * H3 + tid];
    hid[tid] = fmaxf(acc, 0.0f);
    __syncthreads();
    if (tid < OUTD) {
        float o = l2b[tid];
        for (int k = 0; k < H3; ++k) o += hid[k] * l2W[k * OUTD + tid];
        o10[tid] = o;
        out[g * OUTD + tid] = o;
    }
    __syncthreads();
    if (tid == 0) {
        float m = o10[0];
        for (int j = 1; j < OUTD; ++j) m = fmaxf(m, o10[j]);
        float s = 0.0f;
        for (int j = 0; j < OUTD; ++j) s += expf(o10[j] - m);
        float lse = m + logf(s);
        for (int j = 0; j < OUTD; ++j) out[N_GRAPHS * OUTD + g * OUTD + j] = o10[j] - lse;
    }
}

extern "C" void kernel_launch(void* const* d_in, const int* in_sizes, int n_in,
                              void* d_out, int out_size, void* d_ws, size_t ws_size,
                              hipStream_t stream) {
    const float* x      = (const float*)d_in[0];
    const float* W1     = (const float*)d_in[1];
    const float* b1     = (const float*)d_in[2];
    const float* W2     = (const float*)d_in[3];
    const float* b2     = (const float*)d_in[4];
    const float* W3     = (const float*)d_in[5];
    const float* b3     = (const float*)d_in[6];
    const float* lin1_W = (const float*)d_in[7];
    const float* lin1_b = (const float*)d_in[8];
    const float* lin2_W = (const float*)d_in[9];
    const float* lin2_b = (const float*)d_in[10];
    const int* edge_index = (const int*)d_in[11];
    const int* batch      = (const int*)d_in[12];

    char* ws = (char*)d_ws;
    auto alloc = [&](size_t bytes) -> void* {
        void* p = (void*)ws;
        ws += (bytes + 255) & ~(size_t)255;
        return p;
    };
    int*   deg    = (int*)  alloc((size_t)N_NODES * 4);
    int*   part   = (int*)  alloc((size_t)SCAN_BLOCKS * 4);
    int*   pbase  = (int*)  alloc((size_t)SCAN_BLOCKS * 4);
    int*   offs   = (int*)  alloc((size_t)(N_NODES + 1) * 4);
    int*   rank   = (int*)  alloc((size_t)N_EDGES * 4);
    float* dinv   = (float*)alloc((size_t)N_NODES * 4);
    int*   srcs   = (int*)  alloc((size_t)N_EDGES * 4);
    __half* T     = (__half*)alloc((size_t)N_NODES * 128 * 2);
    __half* H     = (__half*)alloc((size_t)N_NODES * 128 * 2);
    _Float16* Wt  = (_Float16*)alloc((size_t)3 * 128 * 128 * 2);
    float* pooled = (float*)alloc((size_t)N_GRAPHS * H3 * 4);

    hipMemsetAsync(deg, 0, (size_t)N_NODES * 4, stream);
    k_deg<<<(N_EDGES + 255) / 256, 256, 0, stream>>>(edge_index, deg, rank);
    k_part<<<SCAN_BLOCKS, 256, 0, stream>>>(deg, part);
    k_scanpart<<<1, 256, 0, stream>>>(part, pbase);
    k_offsets<<<SCAN_BLOCKS, 256, 0, stream>>>(deg, pbase, offs, dinv);
    k_fill<<<(N_EDGES + 255) / 256, 256, 0, stream>>>(edge_index, offs, rank, srcs);
    k_prep<<<288, 256, 0, stream>>>(W1, W2, W3, Wt, pooled);

    const float* bs[3] = {b1, b2, b3};
    for (int l = 0; l < 3; ++l) {
        if (l == 0)
            gemm_mfma<false><<<(N_NODES + 63) / 64, 256, 0, stream>>>(x, Wt, T, N_NODES);
        else
            gemm_mfma<true><<<(N_NODES + 63) / 64, 256, 0, stream>>>(H, Wt + (size_t)l * 16384, T, N_NODES);
        gather_agg<<<(N_NODES + 1) / 2, 128, 0, stream>>>((const __half2*)T, srcs, offs, dinv, bs[l], (__half2*)H);
        pool_kernel<<<N_GRAPHS * POOL_CHUNKS, 256, 0, stream>>>((const __half2*)H, batch, pooled, l * 128);
    }
    mlp_kernel<<<N_GRAPHS, 384, 0, stream>>>(pooled, batch, lin1_W, lin1_b, lin2_W, lin2_b, (float*)d_out);
}

// Round 11
// 306.163 us; speedup vs baseline: 1.1457x; 1.0412x over previous
//
#include <hip/hip_runtime.h>
#include <hip/hip_fp16.h>
#include <math.h>

#define N_NODES 50000
#define N_EDGES 600000
#define N_GRAPHS 64
#define DFEAT 128
#define H3 384
#define OUTD 10
#define SCAN_BLOCKS 196   // 196*256 = 50176 >= 50000
#define POOL_CHUNKS 16    // blocks per graph in pooling
#define APAD 136          // fp16 LDS row pad: 272B stride -> conflict-free b128 reads

typedef _Float16 f16x8 __attribute__((ext_vector_type(8)));
typedef float f32x4 __attribute__((ext_vector_type(4)));
typedef float f32x2 __attribute__((ext_vector_type(2)));

// ---------------- degree histogram (in-degree at dst) + per-edge rank ----------------
__global__ __launch_bounds__(256) void k_deg(const int* __restrict__ ei, int* __restrict__ deg,
                                             int* __restrict__ rank) {
    int e = blockIdx.x * 256 + threadIdx.x;
    if (e >= N_EDGES) return;
    int dst = ei[N_EDGES + e];
    rank[e] = atomicAdd(&deg[dst], 1);
}

// ---------------- hierarchical scan, stage 1: per-block partial sums ----------------
__global__ __launch_bounds__(256) void k_part(const int* __restrict__ deg, int* __restrict__ part) {
    __shared__ int red[256];
    int tid = threadIdx.x;
    int i = blockIdx.x * 256 + tid;
    red[tid] = (i < N_NODES) ? deg[i] : 0;
    __syncthreads();
    for (int s = 128; s > 0; s >>= 1) {
        if (tid < s) red[tid] += red[tid + s];
        __syncthreads();
    }
    if (tid == 0) part[blockIdx.x] = red[0];
}

// ---------------- stage 2: one-block scan of the 196 partials -> exclusive bases ----------------
__global__ __launch_bounds__(256) void k_scanpart(const int* __restrict__ part, int* __restrict__ base) {
    __shared__ int buf[256];
    int tid = threadIdx.x;
    int v = (tid < SCAN_BLOCKS) ? part[tid] : 0;
    buf[tid] = v;
    __syncthreads();
    for (int d = 1; d < 256; d <<= 1) {
        int t = (tid >= d) ? buf[tid - d] : 0;
        __syncthreads();
        buf[tid] += t;
        __syncthreads();
    }
    if (tid < SCAN_BLOCKS) base[tid] = buf[tid] - v;  // exclusive
}

// ---------------- stage 3: block-local scan + base -> offs; fused dinv ----------------
__global__ __launch_bounds__(256) void k_offsets(const int* __restrict__ deg, const int* __restrict__ base,
                                                 int* __restrict__ offs, float* __restrict__ dinv) {
    __shared__ int buf[256];
    int tid = threadIdx.x;
    int i = blockIdx.x * 256 + tid;
    int v = (i < N_NODES) ? deg[i] : 0;
    buf[tid] = v;
    __syncthreads();
    for (int d = 1; d < 256; d <<= 1) {
        int t = (tid >= d) ? buf[tid - d] : 0;
        __syncthreads();
        buf[tid] += t;
        __syncthreads();
    }
    if (i < N_NODES) {
        int excl = base[blockIdx.x] + buf[tid] - v;
        offs[i] = excl;
        dinv[i] = rsqrtf((float)v + 1.0f);
        if (i == N_NODES - 1) offs[N_NODES] = base[blockIdx.x] + buf[tid];  // total == N_EDGES
    }
}

// ---------------- fill CSR buckets: pure scatter, no atomics (rank precomputed) ----------------
__global__ __launch_bounds__(256) void k_fill(const int* __restrict__ ei, const int* __restrict__ offs,
                                              const int* __restrict__ rank, int* __restrict__ srcs) {
    int e = blockIdx.x * 256 + threadIdx.x;
    if (e >= N_EDGES) return;
    int s = ei[e];
    int t = ei[N_EDGES + e];
    srcs[offs[t] + rank[e]] = s;
}

// ---------------- prep: all 3 W's fp32[k][n] -> fp16 transposed [n][k]; zero pooled ----------------
__global__ __launch_bounds__(256) void k_prep(const float* __restrict__ W1, const float* __restrict__ W2,
                                              const float* __restrict__ W3, _Float16* __restrict__ Wt,
                                              float* __restrict__ pooled) {
    int b = blockIdx.x;
    if (b < 192) {
        int idx = b * 256 + threadIdx.x;       // 0..49151
        int l = idx >> 14, r = idx & 16383;
        const float* W = (l == 0) ? W1 : (l == 1) ? W2 : W3;
        int k = r >> 7, n = r & 127;
        Wt[l * 16384 + n * 128 + k] = (_Float16)W[k * 128 + n];
    } else {
        int idx = (b - 192) * 256 + threadIdx.x;
        if (idx < N_GRAPHS * H3) pooled[idx] = 0.0f;
    }
}

// ---------------- T[Mx128](fp8 e4m3) = A[Mx128] @ W (via fp16 MFMA) ----------------
// A is fp32 (layer 1: x) or fp16 (layers 2/3: H). 64 rows/block, 4 waves x 16 rows.
// Operand-swap mfma(b,a,acc): D col(lane&15)=node row, 4 acc regs = 4 consecutive cols.
// Epilogue packs 4 fp32 -> 4 fp8 bytes (one dword store per col-tile).
template <bool A_FP16>
__global__ __launch_bounds__(256) void gemm_mfma(const void* __restrict__ Aptr, const _Float16* __restrict__ Wt,
                                                 unsigned char* __restrict__ T, int M) {
    __shared__ _Float16 As[64 * APAD];    // 17.4 KB
    __shared__ _Float16 Ws[128 * APAD];   // 34.8 KB
    int tid = threadIdx.x;
    int base = blockIdx.x * 64;
    // stage Wt: 128 rows x 16 chunks of 8 f16
    for (int c = tid; c < 2048; c += 256) {
        int n = c >> 4, c8 = (c & 15) << 3;
        *(f16x8*)&Ws[n * APAD + c8] = *(const f16x8*)&Wt[n * 128 + c8];
    }
    // stage A: 64 rows x 16 chunks of 8
    for (int c = tid; c < 1024; c += 256) {
        int r = c >> 4, c8 = (c & 15) << 3;
        int gr = base + r; if (gr >= M) gr = M - 1;
        if (A_FP16) {
            const _Float16* A = (const _Float16*)Aptr;
            *(f16x8*)&As[r * APAD + c8] = *(const f16x8*)&A[(size_t)gr * 128 + c8];
        } else {
            const float* A = (const float*)Aptr;
            const float* src = A + (size_t)gr * 128 + c8;
            float4 v0 = *(const float4*)(src);
            float4 v1 = *(const float4*)(src + 4);
            f16x8 h;
            h[0] = (_Float16)v0.x; h[1] = (_Float16)v0.y; h[2] = (_Float16)v0.z; h[3] = (_Float16)v0.w;
            h[4] = (_Float16)v1.x; h[5] = (_Float16)v1.y; h[6] = (_Float16)v1.z; h[7] = (_Float16)v1.w;
            *(f16x8*)&As[r * APAD + c8] = h;
        }
    }
    __syncthreads();
    int wave = tid >> 6, lane = tid & 63;
    int m = lane & 15, quad = lane >> 4;
    f32x4 acc[8];
#pragma unroll
    for (int ct = 0; ct < 8; ++ct) acc[ct] = (f32x4){0.f, 0.f, 0.f, 0.f};
#pragma unroll
    for (int kc = 0; kc < 4; ++kc) {
        f16x8 a = *(const f16x8*)&As[(wave * 16 + m) * APAD + kc * 32 + quad * 8];
#pragma unroll
        for (int ct = 0; ct < 8; ++ct) {
            f16x8 b = *(const f16x8*)&Ws[(ct * 16 + m) * APAD + kc * 32 + quad * 8];
            acc[ct] = __builtin_amdgcn_mfma_f32_16x16x32_f16(b, a, acc[ct], 0, 0, 0);
        }
    }
    int node = base + wave * 16 + m;
    if (node < M) {
#pragma unroll
        for (int ct = 0; ct < 8; ++ct) {
            int col = ct * 16 + quad * 4;
            int p = __builtin_amdgcn_cvt_pk_fp8_f32(acc[ct][0], acc[ct][1], 0, false);
            p     = __builtin_amdgcn_cvt_pk_fp8_f32(acc[ct][2], acc[ct][3], p, true);
            *(int*)(T + (size_t)node * 128 + col) = p;  // 4B-aligned: col % 4 == 0
        }
    }
}

// ---------------- per-node gather-accumulate: H(fp16) = Ahat * T(fp8) + b ----------------
// 1 wave per node, waves independent. 2 nodes per 128-thread block. Lane reads 2 fp8 dims
// (ushort) and converts via HW v_cvt_pk_f32_fp8. coef recomputed from dinv.
__global__ __launch_bounds__(128) void gather_agg(const unsigned short* __restrict__ T8,
                                                  const int* __restrict__ srcs,
                                                  const int* __restrict__ offs,
                                                  const float* __restrict__ dinv, const float* __restrict__ bias,
                                                  __half2* __restrict__ H2) {
    int node = blockIdx.x * 2 + (threadIdx.x >> 6);
    int lane = threadIdx.x & 63;   // dims 2*lane, 2*lane+1
    if (node >= N_NODES) return;
    float di = dinv[node];
    float2 b2 = *(const float2*)(bias + lane * 2);
    f32x2 sf = __builtin_amdgcn_cvt_pk_f32_fp8((int)T8[(size_t)node * 64 + lane], false);
    float sx = 0.0f, sy = 0.0f;  // edge-sum, weighted by dinv[s] only
    int lo = offs[node], hi = offs[node + 1];
    int e = lo;
    for (; e + 8 <= hi; e += 8) {
        int s0 = srcs[e + 0], s1 = srcs[e + 1], s2 = srcs[e + 2], s3 = srcs[e + 3];
        int s4 = srcs[e + 4], s5 = srcs[e + 5], s6 = srcs[e + 6], s7 = srcs[e + 7];
        float c0 = dinv[s0], c1 = dinv[s1], c2 = dinv[s2], c3 = dinv[s3];
        float c4 = dinv[s4], c5 = dinv[s5], c6 = dinv[s6], c7 = dinv[s7];
        int u0 = T8[(size_t)s0 * 64 + lane];
        int u1 = T8[(size_t)s1 * 64 + lane];
        int u2 = T8[(size_t)s2 * 64 + lane];
        int u3 = T8[(size_t)s3 * 64 + lane];
        int u4 = T8[(size_t)s4 * 64 + lane];
        int u5 = T8[(size_t)s5 * 64 + lane];
        int u6 = T8[(size_t)s6 * 64 + lane];
        int u7 = T8[(size_t)s7 * 64 + lane];
        f32x2 t0 = __builtin_amdgcn_cvt_pk_f32_fp8(u0, false);
        f32x2 t1 = __builtin_amdgcn_cvt_pk_f32_fp8(u1, false);
        f32x2 t2 = __builtin_amdgcn_cvt_pk_f32_fp8(u2, false);
        f32x2 t3 = __builtin_amdgcn_cvt_pk_f32_fp8(u3, false);
        f32x2 t4 = __builtin_amdgcn_cvt_pk_f32_fp8(u4, false);
        f32x2 t5 = __builtin_amdgcn_cvt_pk_f32_fp8(u5, false);
        f32x2 t6 = __builtin_amdgcn_cvt_pk_f32_fp8(u6, false);
        f32x2 t7 = __builtin_amdgcn_cvt_pk_f32_fp8(u7, false);
        sx += t0.x * c0; sy += t0.y * c0;
        sx += t1.x * c1; sy += t1.y * c1;
        sx += t2.x * c2; sy += t2.y * c2;
        sx += t3.x * c3; sy += t3.y * c3;
        sx += t4.x * c4; sy += t4.y * c4;
        sx += t5.x * c5; sy += t5.y * c5;
        sx += t6.x * c6; sy += t6.y * c6;
        sx += t7.x * c7; sy += t7.y * c7;
    }
    for (; e + 4 <= hi; e += 4) {
        int s0 = srcs[e + 0], s1 = srcs[e + 1], s2 = srcs[e + 2], s3 = srcs[e + 3];
        float c0 = dinv[s0], c1 = dinv[s1], c2 = dinv[s2], c3 = dinv[s3];
        f32x2 t0 = __builtin_amdgcn_cvt_pk_f32_fp8((int)T8[(size_t)s0 * 64 + lane], false);
        f32x2 t1 = __builtin_amdgcn_cvt_pk_f32_fp8((int)T8[(size_t)s1 * 64 + lane], false);
        f32x2 t2 = __builtin_amdgcn_cvt_pk_f32_fp8((int)T8[(size_t)s2 * 64 + lane], false);
        f32x2 t3 = __builtin_amdgcn_cvt_pk_f32_fp8((int)T8[(size_t)s3 * 64 + lane], false);
        sx += t0.x * c0; sy += t0.y * c0;
        sx += t1.x * c1; sy += t1.y * c1;
        sx += t2.x * c2; sy += t2.y * c2;
        sx += t3.x * c3; sy += t3.y * c3;
    }
    for (; e < hi; ++e) {
        int s = srcs[e];
        float c = dinv[s];
        f32x2 t = __builtin_amdgcn_cvt_pk_f32_fp8((int)T8[(size_t)s * 64 + lane], false);
        sx += t.x * c; sy += t.y * c;
    }
    float accx = di * sx + sf.x * (di * di) + b2.x;
    float accy = di * sy + sf.y * (di * di) + b2.y;
    H2[(size_t)node * 64 + lane] = __floats2half2_rn(accx, accy);
}

// ---------------- segment-sum pooling, chunked, fp16 H (batch sorted) ----------------
// 256 threads = 4 rows x 64 lane-pairs (__half2 = 2 dims per lane).
__global__ __launch_bounds__(256) void pool_kernel(const __half2* __restrict__ H2, const int* __restrict__ batch,
                                                   float* __restrict__ pooled, int colOff) {
    __shared__ int bounds[2];
    __shared__ float2 red[256];
    int g = blockIdx.x >> 4;        // / POOL_CHUNKS
    int chunk = blockIdx.x & (POOL_CHUNKS - 1);
    int tid = threadIdx.x;
    int d2 = tid & 63, sub = tid >> 6;  // 4 row-accumulators
    if (tid < 2) {
        int target = g + tid;  // lower_bound(batch, target)
        int lo = 0, hi = N_NODES;
        while (lo < hi) {
            int mid = (lo + hi) >> 1;
            if (batch[mid] < target) lo = mid + 1; else hi = mid;
        }
        bounds[tid] = lo;
    }
    __syncthreads();
    int lo = bounds[0], hi = bounds[1];
    int n = hi - lo;
    int per = (n + POOL_CHUNKS - 1) / POOL_CHUNKS;
    int s = lo + chunk * per;
    int e = s + per; if (e > hi) e = hi;
    float ax = 0.0f, ay = 0.0f;
    for (int r = s + sub; r < e; r += 4) {
        float2 v = __half22float2(H2[(size_t)r * 64 + d2]);
        ax += v.x; ay += v.y;
    }
    red[tid] = make_float2(ax, ay);
    __syncthreads();
    if (sub == 0 && s < e) {
        float2 v0 = red[d2], v1 = red[64 + d2], v2 = red[128 + d2], v3 = red[192 + d2];
        float vx = v0.x + v1.x + v2.x + v3.x;
        float vy = v0.y + v1.y + v2.y + v3.y;
        atomicAdd(&pooled[g * H3 + colOff + d2 * 2],     vx);
        atomicAdd(&pooled[g * H3 + colOff + d2 * 2 + 1], vy);
    }
}

// ---------------- MLP head + log_softmax, one block per graph; cnt via binary search ----------------
__global__ __launch_bounds__(384) void mlp_kernel(const float* __restrict__ pooled,
                                                  const int* __restrict__ batch,
                                                  const float* __restrict__ l1W, const float* __restrict__ l1b,
                                                  const float* __restrict__ l2W, const float* __restrict__ l2b,
                                                  float* __restrict__ out) {
    __shared__ float p[H3];
    __shared__ float hid[H3];
    __shared__ float o10[OUTD];
    __shared__ int bnd[2];
    int g = blockIdx.x, tid = threadIdx.x;
    if (tid < 2) {
        int target = g + tid;  // lower_bound(batch, target)
        int lo = 0, hi = N_NODES;
        while (lo < hi) {
            int mid = (lo + hi) >> 1;
            if (batch[mid] < target) lo = mid + 1; else hi = mid;
        }
        bnd[tid] = lo;
    }
    __syncthreads();
    float inv = 1.0f / fmaxf((float)(bnd[1] - bnd[0]), 1.0f);
    p[tid] = pooled[g * H3 + tid] * inv;
    __syncthreads();
    float acc = l1b[tid];
    for (int k = 0; k < H3; ++k) acc += p[k] * l1W[k * H3 + tid];
    hid[tid] = fmaxf(acc, 0.0f);
    __syncthreads();
    if (tid < OUTD) {
        float o = l2b[tid];
        for (int k = 0; k < H3; ++k) o += hid[k] * l2W[k * OUTD + tid];
        o10[tid] = o;
        out[g * OUTD + tid] = o;
    }
    __syncthreads();
    if (tid == 0) {
        float m = o10[0];
        for (int j = 1; j < OUTD; ++j) m = fmaxf(m, o10[j]);
        float s = 0.0f;
        for (int j = 0; j < OUTD; ++j) s += expf(o10[j] - m);
        float lse = m + logf(s);
        for (int j = 0; j < OUTD; ++j) out[N_GRAPHS * OUTD + g * OUTD + j] = o10[j] - lse;
    }
}

extern "C" void kernel_launch(void* const* d_in, const int* in_sizes, int n_in,
                              void* d_out, int out_size, void* d_ws, size_t ws_size,
                              hipStream_t stream) {
    const float* x      = (const float*)d_in[0];
    const float* W1     = (const float*)d_in[1];
    const float* b1     = (const float*)d_in[2];
    const float* W2     = (const float*)d_in[3];
    const float* b2     = (const float*)d_in[4];
    const float* W3     = (const float*)d_in[5];
    const float* b3     = (const float*)d_in[6];
    const float* lin1_W = (const float*)d_in[7];
    const float* lin1_b = (const float*)d_in[8];
    const float* lin2_W = (const float*)d_in[9];
    const float* lin2_b = (const float*)d_in[10];
    const int* edge_index = (const int*)d_in[11];
    const int* batch      = (const int*)d_in[12];

    char* ws = (char*)d_ws;
    auto alloc = [&](size_t bytes) -> void* {
        void* p = (void*)ws;
        ws += (bytes + 255) & ~(size_t)255;
        return p;
    };
    int*   deg    = (int*)  alloc((size_t)N_NODES * 4);
    int*   part   = (int*)  alloc((size_t)SCAN_BLOCKS * 4);
    int*   pbase  = (int*)  alloc((size_t)SCAN_BLOCKS * 4);
    int*   offs   = (int*)  alloc((size_t)(N_NODES + 1) * 4);
    int*   rank   = (int*)  alloc((size_t)N_EDGES * 4);
    float* dinv   = (float*)alloc((size_t)N_NODES * 4);
    int*   srcs   = (int*)  alloc((size_t)N_EDGES * 4);
    unsigned char* T = (unsigned char*)alloc((size_t)N_NODES * 128);
    __half* H     = (__half*)alloc((size_t)N_NODES * 128 * 2);
    _Float16* Wt  = (_Float16*)alloc((size_t)3 * 128 * 128 * 2);
    float* pooled = (float*)alloc((size_t)N_GRAPHS * H3 * 4);

    hipMemsetAsync(deg, 0, (size_t)N_NODES * 4, stream);
    k_deg<<<(N_EDGES + 255) / 256, 256, 0, stream>>>(edge_index, deg, rank);
    k_part<<<SCAN_BLOCKS, 256, 0, stream>>>(deg, part);
    k_scanpart<<<1, 256, 0, stream>>>(part, pbase);
    k_offsets<<<SCAN_BLOCKS, 256, 0, stream>>>(deg, pbase, offs, dinv);
    k_fill<<<(N_EDGES + 255) / 256, 256, 0, stream>>>(edge_index, offs, rank, srcs);
    k_prep<<<288, 256, 0, stream>>>(W1, W2, W3, Wt, pooled);

    const float* bs[3] = {b1, b2, b3};
    for (int l = 0; l < 3; ++l) {
        if (l == 0)
            gemm_mfma<false><<<(N_NODES + 63) / 64, 256, 0, stream>>>(x, Wt, T, N_NODES);
        else
            gemm_mfma<true><<<(N_NODES + 63) / 64, 256, 0, stream>>>(H, Wt + (size_t)l * 16384, T, N_NODES);
        gather_agg<<<(N_NODES + 1) / 2, 128, 0, stream>>>((const unsigned short*)T, srcs, offs, dinv, bs[l], (__half2*)H);
        pool_kernel<<<N_GRAPHS * POOL_CHUNKS, 256, 0, stream>>>((const __half2*)H, batch, pooled, l * 128);
    }
    mlp_kernel<<<N_GRAPHS, 384, 0, stream>>>(pooled, batch, lin1_W, lin1_b, lin2_W, lin2_b, (float*)d_out);
}